// Round 4
// baseline (266.240 us; speedup 1.0000x reference)
//
#include <hip/hip_runtime.h>
#include <cfloat>

typedef __attribute__((ext_vector_type(8))) short short8;
typedef __attribute__((ext_vector_type(4))) float f32x4;

#define NE 1024
#define EDIM 256
#define HW 1024
#define BSTRIDE (EDIM * HW)        // 262144
#define TOTAL 8388608

// workspace layout (bytes)
#define EMBB_OFF  0                        // ushort[1024*256] bf16 = 512 KB
#define ENORM_OFF (512 * 1024)             // float[1024]
#define HIST_OFF  (ENORM_OFF + 4096)       // int[1024]
#define LOSS_OFF  (HIST_OFF + 4096)        // float accumulator
#define DONE_OFF  (LOSS_OFF + 16)          // int completion counter

// round-to-nearest-even fp32 -> bf16 bits (inputs are finite)
__device__ __forceinline__ unsigned short f2bf(float x) {
    unsigned u = __builtin_bit_cast(unsigned, x);
    return (unsigned short)((u + 0x7fffu + ((u >> 16) & 1u)) >> 16);
}

// ---------------------------------------------------------------------------
// P: emb fp32 [1024][256] -> embB bf16 rows + enorm. 64 blocks x 256 thr,
// 16 threads per code row. Block 0 also zeroes hist/loss/done.
// ---------------------------------------------------------------------------
__global__ void prep_emb(const float* __restrict__ emb,
                         unsigned short* __restrict__ embB,
                         float* __restrict__ enorm,
                         int* __restrict__ hist,
                         float* __restrict__ lossAcc,
                         int* __restrict__ done) {
    int t = threadIdx.x;
    int gid = blockIdx.x * 256 + t;        // 0..16383
    int row = gid >> 4, seg = gid & 15;
    const float4* e4 = (const float4*)(emb + (size_t)row * EDIM) + seg * 4;
    float4 a0 = e4[0], a1 = e4[1], a2 = e4[2], a3 = e4[3];
    float s = a0.x * a0.x + a0.y * a0.y + a0.z * a0.z + a0.w * a0.w
            + a1.x * a1.x + a1.y * a1.y + a1.z * a1.z + a1.w * a1.w
            + a2.x * a2.x + a2.y * a2.y + a2.z * a2.z + a2.w * a2.w
            + a3.x * a3.x + a3.y * a3.y + a3.z * a3.z + a3.w * a3.w;
    short8 v0, v1;
    v0[0] = (short)f2bf(a0.x); v0[1] = (short)f2bf(a0.y);
    v0[2] = (short)f2bf(a0.z); v0[3] = (short)f2bf(a0.w);
    v0[4] = (short)f2bf(a1.x); v0[5] = (short)f2bf(a1.y);
    v0[6] = (short)f2bf(a1.z); v0[7] = (short)f2bf(a1.w);
    v1[0] = (short)f2bf(a2.x); v1[1] = (short)f2bf(a2.y);
    v1[2] = (short)f2bf(a2.z); v1[3] = (short)f2bf(a2.w);
    v1[4] = (short)f2bf(a3.x); v1[5] = (short)f2bf(a3.y);
    v1[6] = (short)f2bf(a3.z); v1[7] = (short)f2bf(a3.w);
    *(short8*)&embB[(size_t)row * EDIM + seg * 16]     = v0;
    *(short8*)&embB[(size_t)row * EDIM + seg * 16 + 8] = v1;
    s += __shfl_xor(s, 1, 64);
    s += __shfl_xor(s, 2, 64);
    s += __shfl_xor(s, 4, 64);
    s += __shfl_xor(s, 8, 64);
    if (seg == 0) enorm[row] = s;
    if (blockIdx.x == 0) {                 // fold memset into this dispatch
        ((int4*)hist)[t] = (int4){0, 0, 0, 0};
        if (t == 0) { lossAcc[0] = 0.f; done[0] = 0; }
    }
}

// ---------------------------------------------------------------------------
// F: fused argmin + gather + loss + hist (+ last-block finalize).
// Block = 32 positions, 256 threads (4 waves), grid 1024.
// LEAN wave tile: wave (mw,nw) = (16-position half, 512-code half).
// A-frags are A[8] = 32 VGPRs (round 3's A[2][8]=64 + launch_bounds(,4)
// forced VGPR_Count=64 -> spill -> MfmaUtil fell to 4.7%). With
// __launch_bounds__(256,2) (the only setting that has produced healthy
// codegen: 108/88 regs rounds 0/2) the ~95-reg live set fits under 128 ->
// 4 waves/SIMD -> 16 waves/CU -> 4 resident blocks of the 1024 grid.
// Waves 0,1 share the code-half-0 B stream (L1 dedup), waves 2,3 half 1.
// B direct from L2-resident embB; no main-loop barriers; direct epilogue.
// ---------------------------------------------------------------------------
__global__ __launch_bounds__(256, 2) void fused_kernel(
        const float* __restrict__ z, const float* __restrict__ emb,
        const unsigned short* __restrict__ embB, const float* __restrict__ enormG,
        float* __restrict__ zq, int* __restrict__ hist,
        float* __restrict__ lossAcc, int* __restrict__ done,
        float* __restrict__ out) {
    __shared__ __align__(16) unsigned short As[32 * 264];   // 16.9 KB
    __shared__ float Ens[NE];
    __shared__ float rv[2][32];
    __shared__ int   ri[2][32];
    __shared__ int   idxm[32];
    __shared__ int   amLast;
    __shared__ float wsum[4];

    int t = threadIdx.x;                   // 0..255
    int m0 = blockIdx.x * 32;
    int b = m0 >> 10, pb = m0 & 1023;
    const float* zb  = z  + (size_t)b * BSTRIDE + pb;
    float*       zqb = zq + (size_t)b * BSTRIDE + pb;

    for (int j = t; j < NE; j += 256) Ens[j] = enormG[j];

    int pq = t & 7, cg = t >> 3;           // pq: position quad, cg: 8-ch group
    {   // stage A: 8 independent float4 loads along p, packed short8 writes
        const float* zp = zb + pq * 4;
        float4 zv[8];
#pragma unroll
        for (int v = 0; v < 8; ++v)
            zv[v] = *(const float4*)&zp[(size_t)(cg * 8 + v) * HW];
#pragma unroll
        for (int j = 0; j < 4; ++j) {
            short8 w8;
#pragma unroll
            for (int v = 0; v < 8; ++v) {
                float x = (j == 0) ? zv[v].x : (j == 1) ? zv[v].y
                        : (j == 2) ? zv[v].z : zv[v].w;
                w8[v] = (short)f2bf(x);
            }
            *(short8*)&As[(pq * 4 + j) * 264 + cg * 8] = w8;
        }
    }
    __syncthreads();

    int w = t >> 6, l = t & 63, lm = l & 15, q = l >> 4;
    int mw = w & 1, nw = w >> 1;           // mw: 16-pos half, nw: 512-code half

    short8 A[8];
#pragma unroll
    for (int ks = 0; ks < 8; ++ks)
        A[ks] = *(const short8*)&As[(mw * 16 + lm) * 264 + ks * 32 + q * 8];

    float bd[4]; int bi[4];
#pragma unroll
    for (int i = 0; i < 4; ++i) { bd[i] = FLT_MAX; bi[i] = 0x7fffffff; }

    // main loop: 32 col-frags of 16 codes, B direct from L2, no barriers.
    const short8* eB8 = (const short8*)embB;
#pragma unroll 2
    for (int ct = 0; ct < 32; ++ct) {
        int code = nw * 512 + ct * 16 + lm;
        const short8* bp = eB8 + (size_t)code * 32 + q;
        f32x4 aa = {0,0,0,0}, ab = {0,0,0,0};
#pragma unroll
        for (int ks = 0; ks < 8; ks += 2) {
            short8 Bv0 = bp[ks * 4];
            short8 Bv1 = bp[ks * 4 + 4];
            aa = __builtin_amdgcn_mfma_f32_16x16x32_bf16(A[ks],     Bv0, aa, 0, 0, 0);
            ab = __builtin_amdgcn_mfma_f32_16x16x32_bf16(A[ks + 1], Bv1, ab, 0, 0, 0);
        }
        float en = Ens[code];
#pragma unroll
        for (int r = 0; r < 4; ++r) {
            float d0 = en - 2.f * (aa[r] + ab[r]);
            if (d0 < bd[r]) { bd[r] = d0; bi[r] = code; }
        }
    }

    // reduce across the 16 code-columns (lanes sharing q)
#pragma unroll
    for (int off = 1; off < 16; off <<= 1) {
#pragma unroll
        for (int i = 0; i < 4; ++i) {
            float od = __shfl_xor(bd[i], off, 64);
            int   oi = __shfl_xor(bi[i], off, 64);
            if (od < bd[i] || (od == bd[i] && oi < bi[i])) { bd[i] = od; bi[i] = oi; }
        }
    }
    if (lm == 0) {
#pragma unroll
        for (int r = 0; r < 4; ++r) {
            int p = mw * 16 + q * 4 + r;
            rv[nw][p] = bd[r];
            ri[nw][p] = bi[r];
        }
    }
    __syncthreads();
    if (t < 32) {
        float v0 = rv[0][t]; int i0 = ri[0][t];
        float v1 = rv[1][t]; int i1 = ri[1][t];
        int best = (v1 < v0 || (v1 == v0 && i1 < i0)) ? i1 : i0;
        idxm[t] = best;
        atomicAdd(&hist[best], 1);
    }
    __syncthreads();

    {   // epilogue: gather 4 emb rows (8 ch each), re-read z, write z_q, loss
        int p0 = pq * 4;
        float e0[8], e1[8], e2[8], e3[8];
        {
            const float4* a = (const float4*)(emb + (size_t)idxm[p0 + 0] * EDIM) + cg * 2;
            *(float4*)&e0[0] = a[0]; *(float4*)&e0[4] = a[1];
        }
        {
            const float4* a = (const float4*)(emb + (size_t)idxm[p0 + 1] * EDIM) + cg * 2;
            *(float4*)&e1[0] = a[0]; *(float4*)&e1[4] = a[1];
        }
        {
            const float4* a = (const float4*)(emb + (size_t)idxm[p0 + 2] * EDIM) + cg * 2;
            *(float4*)&e2[0] = a[0]; *(float4*)&e2[4] = a[1];
        }
        {
            const float4* a = (const float4*)(emb + (size_t)idxm[p0 + 3] * EDIM) + cg * 2;
            *(float4*)&e3[0] = a[0]; *(float4*)&e3[4] = a[1];
        }
        float zr[32];
#pragma unroll
        for (int v = 0; v < 8; ++v)
            *(float4*)&zr[v * 4] = *(const float4*)&zb[(size_t)(cg * 8 + v) * HW + p0];
        float ls = 0.f;
#pragma unroll
        for (int v = 0; v < 8; ++v) {
            int c = cg * 8 + v;
            float4 qv; qv.x = e0[v]; qv.y = e1[v]; qv.z = e2[v]; qv.w = e3[v];
            *(float4*)&zqb[(size_t)c * HW + p0] = qv;
            float dx = qv.x - zr[v * 4 + 0], dy = qv.y - zr[v * 4 + 1];
            float dz = qv.z - zr[v * 4 + 2], dw = qv.w - zr[v * 4 + 3];
            ls += dx * dx + dy * dy + dz * dz + dw * dw;
        }
#pragma unroll
        for (int off = 32; off; off >>= 1) ls += __shfl_down(ls, off, 64);
        if ((t & 63) == 0) atomicAdd(lossAcc, ls);
    }

    // last-block finalize (replaces the finalize dispatch)
    if (t == 0) {
        __threadfence();
        amLast = (atomicAdd(done, 1) == (int)gridDim.x - 1);
    }
    __syncthreads();
    if (amLast) {
        float s = 0.f;
        for (int j = t; j < NE; j += 256) {
            float p = (float)atomicAdd(&hist[j], 0) * (1.0f / 32768.0f);
            s += p * logf(p + 1e-10f);
        }
#pragma unroll
        for (int off = 32; off; off >>= 1) s += __shfl_down(s, off, 64);
        if ((t & 63) == 0) wsum[t >> 6] = s;
        __syncthreads();
        if (t == 0) {
            float S = wsum[0] + wsum[1] + wsum[2] + wsum[3];
            out[TOTAL]     = 1.25f * atomicAdd(lossAcc, 0.f) / (float)TOTAL;
            out[TOTAL + 1] = expf(-S);
        }
    }
}

extern "C" void kernel_launch(void* const* d_in, const int* in_sizes, int n_in,
                              void* d_out, int out_size, void* d_ws, size_t ws_size,
                              hipStream_t stream) {
    (void)in_sizes; (void)n_in; (void)out_size; (void)ws_size;
    const float* z   = (const float*)d_in[0];
    const float* emb = (const float*)d_in[1];
    float* out = (float*)d_out;
    char* ws = (char*)d_ws;
    unsigned short* embB = (unsigned short*)(ws + EMBB_OFF);
    float* enorm   = (float*)(ws + ENORM_OFF);
    int*   hist    = (int*)(ws + HIST_OFF);
    float* lossAcc = (float*)(ws + LOSS_OFF);
    int*   done    = (int*)(ws + DONE_OFF);

    prep_emb<<<64, 256, 0, stream>>>(emb, embB, enorm, hist, lossAcc, done);
    fused_kernel<<<1024, 256, 0, stream>>>(z, emb, embB, enorm, out, hist,
                                           lossAcc, done, out);
}

// Round 5
// 209.781 us; speedup vs baseline: 1.2691x; 1.2691x over previous
//
#include <hip/hip_runtime.h>
#include <cfloat>

typedef __attribute__((ext_vector_type(8))) short short8;
typedef __attribute__((ext_vector_type(4))) float f32x4;

#define NE 1024
#define EDIM 256
#define HW 1024
#define BSTRIDE (EDIM * HW)        // 262144
#define TOTAL 8388608

// workspace layout (bytes)
#define EMBB_OFF  0                        // ushort[1024*256] bf16 = 512 KB
#define ENORM_OFF (512 * 1024)             // float[1024]
#define HIST_OFF  (ENORM_OFF + 4096)       // int[1024]
#define LOSS_OFF  (HIST_OFF + 4096)        // float accumulator
#define DONE_OFF  (LOSS_OFF + 16)          // int completion counter

// round-to-nearest-even fp32 -> bf16 bits (inputs are finite)
__device__ __forceinline__ unsigned short f2bf(float x) {
    unsigned u = __builtin_bit_cast(unsigned, x);
    return (unsigned short)((u + 0x7fffu + ((u >> 16) & 1u)) >> 16);
}

// ---------------------------------------------------------------------------
// P: emb fp32 [1024][256] -> embB bf16 rows + enorm. 64 blocks x 256 thr,
// 16 threads per code row. Block 0 also zeroes hist/loss/done.
// ---------------------------------------------------------------------------
__global__ void prep_emb(const float* __restrict__ emb,
                         unsigned short* __restrict__ embB,
                         float* __restrict__ enorm,
                         int* __restrict__ hist,
                         float* __restrict__ lossAcc,
                         int* __restrict__ done) {
    int t = threadIdx.x;
    int gid = blockIdx.x * 256 + t;        // 0..16383
    int row = gid >> 4, seg = gid & 15;
    const float4* e4 = (const float4*)(emb + (size_t)row * EDIM) + seg * 4;
    float4 a0 = e4[0], a1 = e4[1], a2 = e4[2], a3 = e4[3];
    float s = a0.x * a0.x + a0.y * a0.y + a0.z * a0.z + a0.w * a0.w
            + a1.x * a1.x + a1.y * a1.y + a1.z * a1.z + a1.w * a1.w
            + a2.x * a2.x + a2.y * a2.y + a2.z * a2.z + a2.w * a2.w
            + a3.x * a3.x + a3.y * a3.y + a3.z * a3.z + a3.w * a3.w;
    short8 v0, v1;
    v0[0] = (short)f2bf(a0.x); v0[1] = (short)f2bf(a0.y);
    v0[2] = (short)f2bf(a0.z); v0[3] = (short)f2bf(a0.w);
    v0[4] = (short)f2bf(a1.x); v0[5] = (short)f2bf(a1.y);
    v0[6] = (short)f2bf(a1.z); v0[7] = (short)f2bf(a1.w);
    v1[0] = (short)f2bf(a2.x); v1[1] = (short)f2bf(a2.y);
    v1[2] = (short)f2bf(a2.z); v1[3] = (short)f2bf(a2.w);
    v1[4] = (short)f2bf(a3.x); v1[5] = (short)f2bf(a3.y);
    v1[6] = (short)f2bf(a3.z); v1[7] = (short)f2bf(a3.w);
    *(short8*)&embB[(size_t)row * EDIM + seg * 16]     = v0;
    *(short8*)&embB[(size_t)row * EDIM + seg * 16 + 8] = v1;
    s += __shfl_xor(s, 1, 64);
    s += __shfl_xor(s, 2, 64);
    s += __shfl_xor(s, 4, 64);
    s += __shfl_xor(s, 8, 64);
    if (seg == 0) enorm[row] = s;
    if (blockIdx.x == 0) {                 // fold memset into this dispatch
        ((int4*)hist)[t] = (int4){0, 0, 0, 0};
        if (t == 0) { lossAcc[0] = 0.f; done[0] = 0; }
    }
}

// ---------------------------------------------------------------------------
// F: fused argmin + gather + loss + hist (+ last-block finalize).
// Recombines the two PROVEN wins:
//  - R0's main loop: B staged in LDS via coalesced short8 loads, A[2][8]
//    frags/wave, 4-acc ILP, 16 MFMA per 8 ds_read_b128. (Direct-L2 B was
//    2-15x worse across R2-R4: per-lane 512B-strided 16B reads serialize.)
//  - R3/R4's small shell: 32-pos block, grid 1024, ~39 KB LDS -> 4 resident
//    blocks/CU (16 waves/CU). R0's 75 KB Es union capped it at 2 blocks/CU,
//    so every tile barrier drained the whole CU; 4 independent blocks
//    overlap each other's barrier drains.
// Wave w owns all 32 positions x the w-th 16-code column of each 64-code
// LDS B-tile; 16 tiles cover NE=1024. launch_bounds(256,2): the only
// setting with healthy regalloc (88-108 VGPR); (,4) collapsed to 48-64 +
// scratch twice (R1/R3-R4).
// ---------------------------------------------------------------------------
__global__ __launch_bounds__(256, 2) void fused_kernel(
        const float* __restrict__ z, const float* __restrict__ emb,
        const unsigned short* __restrict__ embB, const float* __restrict__ enormG,
        float* __restrict__ zq, int* __restrict__ hist,
        float* __restrict__ lossAcc, int* __restrict__ done,
        float* __restrict__ out) {
    // union: As 32x264 bf16 (16.9 KB) during A-stage, Bs 64x264 (33.8 KB) in loop
    __shared__ __align__(16) unsigned short smem[64 * 264];
    __shared__ float Ens[NE];
    __shared__ float rv[4][32];
    __shared__ int   ri[4][32];
    __shared__ int   idxm[32];
    __shared__ int   amLast;
    __shared__ float wsum[4];

    unsigned short* As  = smem;
    unsigned short* Bs  = smem;
    short8*         Bs8 = (short8*)smem;

    int t = threadIdx.x;                   // 0..255
    int m0 = blockIdx.x * 32;
    int b = m0 >> 10, pb = m0 & 1023;
    const float* zb  = z  + (size_t)b * BSTRIDE + pb;
    float*       zqb = zq + (size_t)b * BSTRIDE + pb;

    for (int j = t; j < NE; j += 256) Ens[j] = enormG[j];

    int pq = t & 7, cg = t >> 3;           // pq: position quad, cg: 8-ch group
    {   // stage A: 8 independent float4 loads along p, packed short8 writes
        const float* zp = zb + pq * 4;
        float4 zv[8];
#pragma unroll
        for (int v = 0; v < 8; ++v)
            zv[v] = *(const float4*)&zp[(size_t)(cg * 8 + v) * HW];
#pragma unroll
        for (int j = 0; j < 4; ++j) {
            short8 w8;
#pragma unroll
            for (int v = 0; v < 8; ++v) {
                float x = (j == 0) ? zv[v].x : (j == 1) ? zv[v].y
                        : (j == 2) ? zv[v].z : zv[v].w;
                w8[v] = (short)f2bf(x);
            }
            *(short8*)&As[(pq * 4 + j) * 264 + cg * 8] = w8;
        }
    }
    __syncthreads();

    int w = t >> 6, l = t & 63, lm = l & 15, q = l >> 4;

    short8 A[2][8];                        // all 32 positions, 64 VGPRs
#pragma unroll
    for (int s = 0; s < 2; ++s)
#pragma unroll
        for (int ks = 0; ks < 8; ++ks)
            A[s][ks] = *(const short8*)&As[(s * 16 + lm) * 264 + ks * 32 + q * 8];

    float bd[8]; int bi[8];
#pragma unroll
    for (int i = 0; i < 8; ++i) { bd[i] = FLT_MAX; bi[i] = 0x7fffffff; }

    __syncthreads();   // As consumed; smem becomes the B tile buffer

    const short8* eB8 = (const short8*)embB;
    for (int nt = 0; nt < 16; ++nt) {
        int n0 = nt * 64;
        // stage B tile: 64 rows x 256 k = 2048 short8, coalesced (thread t
        // and t+1 read adjacent 16B; 1 KB per wave-instruction)
#pragma unroll
        for (int i = 0; i < 8; ++i) {
            int slot = i * 256 + t;
            Bs8[(slot >> 5) * 33 + (slot & 31)] = eB8[(size_t)n0 * 32 + slot];
        }
        __syncthreads();
        {
            int cl = w * 16 + lm;          // this wave's code column in tile
            float en = Ens[n0 + cl];
            f32x4 a0a = {0,0,0,0}, a0b = {0,0,0,0};
            f32x4 a1a = {0,0,0,0}, a1b = {0,0,0,0};
#pragma unroll
            for (int ks = 0; ks < 8; ks += 2) {
                short8 Bv0 = *(const short8*)&Bs[cl * 264 + ks * 32 + q * 8];
                short8 Bv1 = *(const short8*)&Bs[cl * 264 + (ks + 1) * 32 + q * 8];
                a0a = __builtin_amdgcn_mfma_f32_16x16x32_bf16(A[0][ks],     Bv0, a0a, 0, 0, 0);
                a1a = __builtin_amdgcn_mfma_f32_16x16x32_bf16(A[1][ks],     Bv0, a1a, 0, 0, 0);
                a0b = __builtin_amdgcn_mfma_f32_16x16x32_bf16(A[0][ks + 1], Bv1, a0b, 0, 0, 0);
                a1b = __builtin_amdgcn_mfma_f32_16x16x32_bf16(A[1][ks + 1], Bv1, a1b, 0, 0, 0);
            }
            int code = n0 + cl;
#pragma unroll
            for (int r = 0; r < 4; ++r) {
                float d0 = en - 2.f * (a0a[r] + a0b[r]);
                if (d0 < bd[r])     { bd[r] = d0;     bi[r] = code; }
                float d1 = en - 2.f * (a1a[r] + a1b[r]);
                if (d1 < bd[4 + r]) { bd[4 + r] = d1; bi[4 + r] = code; }
            }
        }
        __syncthreads();   // B tile consumed
    }

    // reduce across the 16 code-columns (lanes sharing q)
#pragma unroll
    for (int off = 1; off < 16; off <<= 1) {
#pragma unroll
        for (int i = 0; i < 8; ++i) {
            float od = __shfl_xor(bd[i], off, 64);
            int   oi = __shfl_xor(bi[i], off, 64);
            if (od < bd[i] || (od == bd[i] && oi < bi[i])) { bd[i] = od; bi[i] = oi; }
        }
    }
    if (lm == 0) {
#pragma unroll
        for (int s = 0; s < 2; ++s)
#pragma unroll
            for (int r = 0; r < 4; ++r) {
                int p = s * 16 + q * 4 + r;
                rv[w][p] = bd[s * 4 + r];
                ri[w][p] = bi[s * 4 + r];
            }
    }
    __syncthreads();
    if (t < 32) {
        float v = rv[0][t]; int bix = ri[0][t];
#pragma unroll
        for (int j = 1; j < 4; ++j) {
            float vj = rv[j][t]; int ij = ri[j][t];
            if (vj < v || (vj == v && ij < bix)) { v = vj; bix = ij; }
        }
        idxm[t] = bix;
        atomicAdd(&hist[bix], 1);
    }
    __syncthreads();

    {   // epilogue: gather 4 emb rows (8 ch each), re-read z, write z_q, loss
        int p0 = pq * 4;
        float e0[8], e1[8], e2[8], e3[8];
        {
            const float4* a = (const float4*)(emb + (size_t)idxm[p0 + 0] * EDIM) + cg * 2;
            *(float4*)&e0[0] = a[0]; *(float4*)&e0[4] = a[1];
        }
        {
            const float4* a = (const float4*)(emb + (size_t)idxm[p0 + 1] * EDIM) + cg * 2;
            *(float4*)&e1[0] = a[0]; *(float4*)&e1[4] = a[1];
        }
        {
            const float4* a = (const float4*)(emb + (size_t)idxm[p0 + 2] * EDIM) + cg * 2;
            *(float4*)&e2[0] = a[0]; *(float4*)&e2[4] = a[1];
        }
        {
            const float4* a = (const float4*)(emb + (size_t)idxm[p0 + 3] * EDIM) + cg * 2;
            *(float4*)&e3[0] = a[0]; *(float4*)&e3[4] = a[1];
        }
        float zr[32];
#pragma unroll
        for (int v = 0; v < 8; ++v)
            *(float4*)&zr[v * 4] = *(const float4*)&zb[(size_t)(cg * 8 + v) * HW + p0];
        float ls = 0.f;
#pragma unroll
        for (int v = 0; v < 8; ++v) {
            int c = cg * 8 + v;
            float4 qv; qv.x = e0[v]; qv.y = e1[v]; qv.z = e2[v]; qv.w = e3[v];
            *(float4*)&zqb[(size_t)c * HW + p0] = qv;
            float dx = qv.x - zr[v * 4 + 0], dy = qv.y - zr[v * 4 + 1];
            float dz = qv.z - zr[v * 4 + 2], dw = qv.w - zr[v * 4 + 3];
            ls += dx * dx + dy * dy + dz * dz + dw * dw;
        }
#pragma unroll
        for (int off = 32; off; off >>= 1) ls += __shfl_down(ls, off, 64);
        if ((t & 63) == 0) atomicAdd(lossAcc, ls);
    }

    // last-block finalize (replaces the finalize dispatch)
    if (t == 0) {
        __threadfence();
        amLast = (atomicAdd(done, 1) == (int)gridDim.x - 1);
    }
    __syncthreads();
    if (amLast) {
        float s = 0.f;
        for (int j = t; j < NE; j += 256) {
            float p = (float)atomicAdd(&hist[j], 0) * (1.0f / 32768.0f);
            s += p * logf(p + 1e-10f);
        }
#pragma unroll
        for (int off = 32; off; off >>= 1) s += __shfl_down(s, off, 64);
        if ((t & 63) == 0) wsum[t >> 6] = s;
        __syncthreads();
        if (t == 0) {
            float S = wsum[0] + wsum[1] + wsum[2] + wsum[3];
            out[TOTAL]     = 1.25f * atomicAdd(lossAcc, 0.f) / (float)TOTAL;
            out[TOTAL + 1] = expf(-S);
        }
    }
}

extern "C" void kernel_launch(void* const* d_in, const int* in_sizes, int n_in,
                              void* d_out, int out_size, void* d_ws, size_t ws_size,
                              hipStream_t stream) {
    (void)in_sizes; (void)n_in; (void)out_size; (void)ws_size;
    const float* z   = (const float*)d_in[0];
    const float* emb = (const float*)d_in[1];
    float* out = (float*)d_out;
    char* ws = (char*)d_ws;
    unsigned short* embB = (unsigned short*)(ws + EMBB_OFF);
    float* enorm   = (float*)(ws + ENORM_OFF);
    int*   hist    = (int*)(ws + HIST_OFF);
    float* lossAcc = (float*)(ws + LOSS_OFF);
    int*   done    = (int*)(ws + DONE_OFF);

    prep_emb<<<64, 256, 0, stream>>>(emb, embB, enorm, hist, lossAcc, done);
    fused_kernel<<<1024, 256, 0, stream>>>(z, emb, embB, enorm, out, hist,
                                           lossAcc, done, out);
}

// Round 6
// 145.585 us; speedup vs baseline: 1.8288x; 1.4410x over previous
//
#include <hip/hip_runtime.h>
#include <cfloat>

typedef __attribute__((ext_vector_type(8))) short short8;
typedef __attribute__((ext_vector_type(4))) float f32x4;

#define NE 1024
#define EDIM 256
#define HW 1024
#define BSTRIDE (EDIM * HW)        // 262144
#define TOTAL 8388608

// workspace layout (bytes)
#define EMBB_OFF  0                        // ushort[1024*256] bf16 = 512 KB
#define ENORM_OFF (512 * 1024)             // float[1024]
#define HIST_OFF  (ENORM_OFF + 4096)       // int[1024]
#define LOSS_OFF  (HIST_OFF + 4096)        // float accumulator
#define DONE_OFF  (LOSS_OFF + 16)          // int completion counter

#define BUFS (64 * 264)                    // shorts per B buffer (64 codes)

// round-to-nearest-even fp32 -> bf16 bits (inputs are finite)
__device__ __forceinline__ unsigned short f2bf(float x) {
    unsigned u = __builtin_bit_cast(unsigned, x);
    return (unsigned short)((u + 0x7fffu + ((u >> 16) & 1u)) >> 16);
}

// ---------------------------------------------------------------------------
// P: emb fp32 [1024][256] -> embB bf16 rows + enorm. 64 blocks x 256 thr,
// 16 threads per code row. Block 0 also zeroes hist/loss/done.
// ---------------------------------------------------------------------------
__global__ void prep_emb(const float* __restrict__ emb,
                         unsigned short* __restrict__ embB,
                         float* __restrict__ enorm,
                         int* __restrict__ hist,
                         float* __restrict__ lossAcc,
                         int* __restrict__ done) {
    int t = threadIdx.x;
    int gid = blockIdx.x * 256 + t;        // 0..16383
    int row = gid >> 4, seg = gid & 15;
    const float4* e4 = (const float4*)(emb + (size_t)row * EDIM) + seg * 4;
    float4 a0 = e4[0], a1 = e4[1], a2 = e4[2], a3 = e4[3];
    float s = a0.x * a0.x + a0.y * a0.y + a0.z * a0.z + a0.w * a0.w
            + a1.x * a1.x + a1.y * a1.y + a1.z * a1.z + a1.w * a1.w
            + a2.x * a2.x + a2.y * a2.y + a2.z * a2.z + a2.w * a2.w
            + a3.x * a3.x + a3.y * a3.y + a3.z * a3.z + a3.w * a3.w;
    short8 v0, v1;
    v0[0] = (short)f2bf(a0.x); v0[1] = (short)f2bf(a0.y);
    v0[2] = (short)f2bf(a0.z); v0[3] = (short)f2bf(a0.w);
    v0[4] = (short)f2bf(a1.x); v0[5] = (short)f2bf(a1.y);
    v0[6] = (short)f2bf(a1.z); v0[7] = (short)f2bf(a1.w);
    v1[0] = (short)f2bf(a2.x); v1[1] = (short)f2bf(a2.y);
    v1[2] = (short)f2bf(a2.z); v1[3] = (short)f2bf(a2.w);
    v1[4] = (short)f2bf(a3.x); v1[5] = (short)f2bf(a3.y);
    v1[6] = (short)f2bf(a3.z); v1[7] = (short)f2bf(a3.w);
    *(short8*)&embB[(size_t)row * EDIM + seg * 16]     = v0;
    *(short8*)&embB[(size_t)row * EDIM + seg * 16 + 8] = v1;
    s += __shfl_xor(s, 1, 64);
    s += __shfl_xor(s, 2, 64);
    s += __shfl_xor(s, 4, 64);
    s += __shfl_xor(s, 8, 64);
    if (seg == 0) enorm[row] = s;
    if (blockIdx.x == 0) {                 // fold memset into this dispatch
        ((int4*)hist)[t] = (int4){0, 0, 0, 0};
        if (t == 0) { lossAcc[0] = 0.f; done[0] = 0; }
    }
}

// ---------------------------------------------------------------------------
// F: fused argmin + gather + loss + hist (+ last-block finalize).
// R0's proven geometry (64-pos block, 256 thr, grid 512, A[2][8]/wave,
// 512 MFMA/wave) with the main loop rebuilt as a double-buffered,
// ONE-barrier-per-tile pipeline (T14/T3-minimum):
//   per tile: issue next tile's 8x16B global loads -> regs (fly across the
//   whole compute phase); barrier; 32 MFMA + 16 ds_read_b128 from buf[cur];
//   ds_write prefetched regs -> buf[cur^1].
// R0 instead cold-staged each tile behind a full barrier drain (16 loads ->
// vmcnt(0) -> barrier -> compute), 8x per block: that latency unit was the
// bottleneck (MfmaUtil 7%, all pipes <10%). Ladder evidence R0/R2/R5 says
// per-tile fixed latency dominates, so overlap it, don't multiply it.
// Direct epilogue (proven R3-R5) removes the 69.6 KB Es union; LDS ~73 KB,
// 2 blocks/CU (grid 512 caps residency anyway -> VGPR up to ~250 is free;
// launch_bounds(256,2) is the only setting with healthy codegen).
// ---------------------------------------------------------------------------
__global__ __launch_bounds__(256, 2) void fused_kernel(
        const float* __restrict__ z, const float* __restrict__ emb,
        const unsigned short* __restrict__ embB, const float* __restrict__ enormG,
        float* __restrict__ zq, int* __restrict__ hist,
        float* __restrict__ lossAcc, int* __restrict__ done,
        float* __restrict__ out) {
    // buf0 (unions with the A-stage tile) + buf1: 2 x 64 codes x 264 shorts
    __shared__ __align__(16) unsigned short smem[2 * BUFS];   // 67.6 KB
    __shared__ float Ens[NE];
    __shared__ float rv[2][64];
    __shared__ int   ri[2][64];
    __shared__ int   idxm[64];
    __shared__ int   amLast;
    __shared__ float wsum[4];

    int t = threadIdx.x;                   // 0..255
    int m0 = blockIdx.x * 64;
    int b = m0 >> 10, pb = m0 & 1023;
    const float* zb  = z  + (size_t)b * BSTRIDE + pb;
    float*       zqb = zq + (size_t)b * BSTRIDE + pb;

    for (int j = t; j < NE; j += 256) Ens[j] = enormG[j];

    int pq = t & 15, cg = t >> 4;          // p-quad 0..15, 16-ch group 0..15
    {   // stage A: 64 pos x 256 ch, float4 loads along p, short8 LDS writes
        unsigned short* As = smem;
        const float* zp = zb + pq * 4;
#pragma unroll
        for (int h = 0; h < 2; ++h) {
            float4 zv[8];
#pragma unroll
            for (int v = 0; v < 8; ++v)
                zv[v] = *(const float4*)&zp[(size_t)(cg * 16 + h * 8 + v) * HW];
#pragma unroll
            for (int j = 0; j < 4; ++j) {
                short8 w8;
#pragma unroll
                for (int v = 0; v < 8; ++v) {
                    float x = (j == 0) ? zv[v].x : (j == 1) ? zv[v].y
                            : (j == 2) ? zv[v].z : zv[v].w;
                    w8[v] = (short)f2bf(x);
                }
                *(short8*)&As[(pq * 4 + j) * 264 + cg * 16 + h * 8] = w8;
            }
        }
    }
    __syncthreads();

    int w = t >> 6, l = t & 63, lm = l & 15, q = l >> 4;
    int mw = w >> 1, nw = w & 1;           // mw: 32-pos half, nw: 32-code half

    // issue tile-0 prefetch first so it flies under the A-frag ds_reads
    const short8* eB8 = (const short8*)embB;
    short8 pref[8];
#pragma unroll
    for (int i = 0; i < 8; ++i) {
        int slot = i * 256 + t;
        pref[i] = eB8[(size_t)(slot >> 5) * 32 + (slot & 31)];
    }

    short8 A[2][8];                        // all 64 pos (2 m-frags x 8 k-slices)
#pragma unroll
    for (int s = 0; s < 2; ++s)
#pragma unroll
        for (int ks = 0; ks < 8; ++ks)
            A[s][ks] = *(const short8*)&smem[(mw * 32 + s * 16 + lm) * 264 + ks * 32 + q * 8];

    float bd[8]; int bi[8];
#pragma unroll
    for (int i = 0; i < 8; ++i) { bd[i] = FLT_MAX; bi[i] = 0x7fffffff; }

    __syncthreads();   // A consumed; smem becomes the double-buffered B tile

    {   // write tile 0 into buf0
        short8* Bw = (short8*)smem;
#pragma unroll
        for (int i = 0; i < 8; ++i) {
            int slot = i * 256 + t;
            Bw[(slot >> 5) * 33 + (slot & 31)] = pref[i];
        }
    }

#pragma unroll 2
    for (int nt = 0; nt < 16; ++nt) {
        int cur = nt & 1;
        if (nt < 15) {                     // prefetch next tile -> regs
            int n1 = (nt + 1) * 64;
#pragma unroll
            for (int i = 0; i < 8; ++i) {
                int slot = i * 256 + t;
                pref[i] = eB8[(size_t)(n1 + (slot >> 5)) * 32 + (slot & 31)];
            }
        }
        __syncthreads();                   // buf[cur] writes visible
        const unsigned short* Bc = smem + cur * BUFS;
        int n0 = nt * 64;
#pragma unroll
        for (int nf = 0; nf < 2; ++nf) {
            int cl = nw * 32 + nf * 16 + lm;
            float en = Ens[n0 + cl];
            f32x4 a0a = {0,0,0,0}, a0b = {0,0,0,0};
            f32x4 a1a = {0,0,0,0}, a1b = {0,0,0,0};
#pragma unroll
            for (int ks = 0; ks < 8; ks += 2) {
                short8 Bv0 = *(const short8*)&Bc[cl * 264 + ks * 32 + q * 8];
                short8 Bv1 = *(const short8*)&Bc[cl * 264 + (ks + 1) * 32 + q * 8];
                a0a = __builtin_amdgcn_mfma_f32_16x16x32_bf16(A[0][ks],     Bv0, a0a, 0, 0, 0);
                a1a = __builtin_amdgcn_mfma_f32_16x16x32_bf16(A[1][ks],     Bv0, a1a, 0, 0, 0);
                a0b = __builtin_amdgcn_mfma_f32_16x16x32_bf16(A[0][ks + 1], Bv1, a0b, 0, 0, 0);
                a1b = __builtin_amdgcn_mfma_f32_16x16x32_bf16(A[1][ks + 1], Bv1, a1b, 0, 0, 0);
            }
            int code = n0 + cl;
#pragma unroll
            for (int r = 0; r < 4; ++r) {
                float d0 = en - 2.f * (a0a[r] + a0b[r]);
                if (d0 < bd[r])     { bd[r] = d0;     bi[r] = code; }
                float d1 = en - 2.f * (a1a[r] + a1b[r]);
                if (d1 < bd[4 + r]) { bd[4 + r] = d1; bi[4 + r] = code; }
            }
        }
        if (nt < 15) {                     // drain prefetch into the other buf
            short8* Bw = (short8*)(smem + (cur ^ 1) * BUFS);
#pragma unroll
            for (int i = 0; i < 8; ++i) {
                int slot = i * 256 + t;
                Bw[(slot >> 5) * 33 + (slot & 31)] = pref[i];
            }
        }
    }

    // reduce across the 16 code-columns (lanes sharing q)
#pragma unroll
    for (int off = 1; off < 16; off <<= 1) {
#pragma unroll
        for (int i = 0; i < 8; ++i) {
            float od = __shfl_xor(bd[i], off, 64);
            int   oi = __shfl_xor(bi[i], off, 64);
            if (od < bd[i] || (od == bd[i] && oi < bi[i])) { bd[i] = od; bi[i] = oi; }
        }
    }
    if (lm == 0) {
#pragma unroll
        for (int s = 0; s < 2; ++s)
#pragma unroll
            for (int r = 0; r < 4; ++r) {
                int p = mw * 32 + s * 16 + q * 4 + r;
                rv[nw][p] = bd[s * 4 + r];
                ri[nw][p] = bi[s * 4 + r];
            }
    }
    __syncthreads();
    if (t < 64) {
        float v0 = rv[0][t]; int i0 = ri[0][t];
        float v1 = rv[1][t]; int i1 = ri[1][t];
        int best = (v1 < v0 || (v1 == v0 && i1 < i0)) ? i1 : i0;
        idxm[t] = best;
        atomicAdd(&hist[best], 1);
    }
    __syncthreads();

    {   // epilogue: gather 4 emb rows x 16 ch (two 8-ch halves), re-read z,
        // write z_q (float4 along p), accumulate loss
        int p0 = pq * 4;
        int k0 = idxm[p0], k1 = idxm[p0 + 1], k2 = idxm[p0 + 2], k3 = idxm[p0 + 3];
        float ls = 0.f;
#pragma unroll
        for (int h = 0; h < 2; ++h) {
            int cb = cg * 16 + h * 8;
            float e0[8], e1[8], e2[8], e3[8];
            {
                const float4* a = (const float4*)(emb + (size_t)k0 * EDIM) + (cb >> 2);
                *(float4*)&e0[0] = a[0]; *(float4*)&e0[4] = a[1];
            }
            {
                const float4* a = (const float4*)(emb + (size_t)k1 * EDIM) + (cb >> 2);
                *(float4*)&e1[0] = a[0]; *(float4*)&e1[4] = a[1];
            }
            {
                const float4* a = (const float4*)(emb + (size_t)k2 * EDIM) + (cb >> 2);
                *(float4*)&e2[0] = a[0]; *(float4*)&e2[4] = a[1];
            }
            {
                const float4* a = (const float4*)(emb + (size_t)k3 * EDIM) + (cb >> 2);
                *(float4*)&e3[0] = a[0]; *(float4*)&e3[4] = a[1];
            }
            float zr[32];
#pragma unroll
            for (int v = 0; v < 8; ++v)
                *(float4*)&zr[v * 4] = *(const float4*)&zb[(size_t)(cb + v) * HW + p0];
#pragma unroll
            for (int v = 0; v < 8; ++v) {
                float4 qv; qv.x = e0[v]; qv.y = e1[v]; qv.z = e2[v]; qv.w = e3[v];
                *(float4*)&zqb[(size_t)(cb + v) * HW + p0] = qv;
                float dx = qv.x - zr[v * 4 + 0], dy = qv.y - zr[v * 4 + 1];
                float dz = qv.z - zr[v * 4 + 2], dw = qv.w - zr[v * 4 + 3];
                ls += dx * dx + dy * dy + dz * dz + dw * dw;
            }
        }
#pragma unroll
        for (int off = 32; off; off >>= 1) ls += __shfl_down(ls, off, 64);
        if ((t & 63) == 0) atomicAdd(lossAcc, ls);
    }

    // last-block finalize (replaces the finalize dispatch)
    if (t == 0) {
        __threadfence();
        amLast = (atomicAdd(done, 1) == (int)gridDim.x - 1);
    }
    __syncthreads();
    if (amLast) {
        float s = 0.f;
        for (int j = t; j < NE; j += 256) {
            float p = (float)atomicAdd(&hist[j], 0) * (1.0f / 32768.0f);
            s += p * logf(p + 1e-10f);
        }
#pragma unroll
        for (int off = 32; off; off >>= 1) s += __shfl_down(s, off, 64);
        if ((t & 63) == 0) wsum[t >> 6] = s;
        __syncthreads();
        if (t == 0) {
            float S = wsum[0] + wsum[1] + wsum[2] + wsum[3];
            out[TOTAL]     = 1.25f * atomicAdd(lossAcc, 0.f) / (float)TOTAL;
            out[TOTAL + 1] = expf(-S);
        }
    }
}

extern "C" void kernel_launch(void* const* d_in, const int* in_sizes, int n_in,
                              void* d_out, int out_size, void* d_ws, size_t ws_size,
                              hipStream_t stream) {
    (void)in_sizes; (void)n_in; (void)out_size; (void)ws_size;
    const float* z   = (const float*)d_in[0];
    const float* emb = (const float*)d_in[1];
    float* out = (float*)d_out;
    char* ws = (char*)d_ws;
    unsigned short* embB = (unsigned short*)(ws + EMBB_OFF);
    float* enorm   = (float*)(ws + ENORM_OFF);
    int*   hist    = (int*)(ws + HIST_OFF);
    float* lossAcc = (float*)(ws + LOSS_OFF);
    int*   done    = (int*)(ws + DONE_OFF);

    prep_emb<<<64, 256, 0, stream>>>(emb, embB, enorm, hist, lossAcc, done);
    fused_kernel<<<512, 256, 0, stream>>>(z, emb, embB, enorm, out, hist,
                                          lossAcc, done, out);
}